// Round 13
// baseline (336.062 us; speedup 1.0000x reference)
//
#include <hip/hip_runtime.h>
#include <math.h>

// Problem constants (shapes fixed by the reference)
#define D 128
#define HH 128
#define CC 64
#define NLAYERS 3
#define LN_EPS 1e-5f

typedef __attribute__((ext_vector_type(8))) short bf16x8;
typedef __attribute__((ext_vector_type(4))) float f32x4;
typedef unsigned short u16;
typedef unsigned int u32;

// round-to-nearest-even fp32 -> bf16 bits
__device__ __forceinline__ u16 f2bf(float f) {
    u32 u = __float_as_uint(f);
    u32 r = u + 0x7FFFu + ((u >> 16) & 1u);
    return (u16)(r >> 16);
}
__device__ __forceinline__ float bf2f(u16 h) {
    return __uint_as_float(((u32)h) << 16);
}

// async global->LDS DMA, 16 B per lane (dest = wave-uniform base + lane*16)
__device__ __forceinline__ void gload_lds16(const void* g, void* l) {
    __builtin_amdgcn_global_load_lds(
        (const __attribute__((address_space(1))) void*)g,
        (__attribute__((address_space(3))) void*)l, 16, 0, 0);
}

// ---------------------------------------------------------------------------
// k_prep: fused setup — x->bf16 (float4) + tile Wg/W1/W2 + edge counting
// (cnt zeroed by hipMemsetAsync before this launch).
// Tiled layout: [kc][q][n][j], k = kc*32 + q*8 + j.
// ---------------------------------------------------------------------------
__global__ void k_prep(const float* __restrict__ x, u16* __restrict__ xh,
                       const float* __restrict__ Wg, u16* __restrict__ WgtH,
                       const float* __restrict__ W1, u16* __restrict__ W1tH,
                       const float* __restrict__ W2, u16* __restrict__ W2tH,
                       u16* __restrict__ W2tL,
                       const int* __restrict__ dst, int* __restrict__ cnt,
                       int N, int E)
{
    int i = blockIdx.x * blockDim.x + threadIdx.x;
    // seg 0: x -> bf16 hi, 4 elements per thread (float4 load, ushort4 store)
    int nx4 = N * (D / 4);
    if (i < nx4) {
        float4 v = *(const float4*)(x + (size_t)i * 4);
        int row = i >> 5, c = (i & 31) << 2;
        ushort4 o;
        o.x = f2bf(v.x); o.y = f2bf(v.y); o.z = f2bf(v.z); o.w = f2bf(v.w);
        *(ushort4*)&xh[(size_t)row * 512 + c] = o;
        return;
    }
    i -= nx4;
    // seg 1: Wg (3 stacked 128x128 matrices; layout linear in kc)
    if (i < NLAYERS * D * HH) {
        int k = i >> 7, n = i & 127;
        int kc = k >> 5, q = (k >> 3) & 3, j = k & 7;
        WgtH[(((kc * 4 + q) << 7) + n) * 8 + j] = f2bf(Wg[i]);
        return;
    }
    i -= NLAYERS * D * HH;
    // seg 2: W1 (512x128)
    if (i < (D + NLAYERS * HH) * HH) {
        int k = i >> 7, n = i & 127;
        int kc = k >> 5, q = (k >> 3) & 3, j = k & 7;
        W1tH[(((kc * 4 + q) << 7) + n) * 8 + j] = f2bf(W1[i]);
        return;
    }
    i -= (D + NLAYERS * HH) * HH;
    // seg 3: W2 (128x64), hi + lo (split-3 in mlp phase 2)
    if (i < HH * CC) {
        int k = i >> 6, n = i & 63;
        int kc = k >> 5, q = (k >> 3) & 3, j = k & 7;
        float v = W2[i];
        u16 h = f2bf(v);
        int o = (((kc * 4 + q) << 6) + n) * 8 + j;
        W2tH[o] = h;
        W2tL[o] = f2bf(v - bf2f(h));
        return;
    }
    i -= HH * CC;
    // seg 4: edge degree count (cnt pre-zeroed by hipMemsetAsync)
    if (i < E) atomicAdd(&cnt[dst[i]], 1);
}

// ---------------------------------------------------------------------------
// CSR build: scan_a -> scan_c -> scatter. Separate small launches:
// grid.sync() on MI355X costs ~100 µs/barrier (round-2: fused coop = 527 µs).
// ---------------------------------------------------------------------------

// shuffle-based block scan: 2 barriers
__global__ void k_scan_a(const int* __restrict__ cnt, int* __restrict__ rowptr,
                         int* __restrict__ bsum, int N) {
    __shared__ int ws[16];
    int tid  = threadIdx.x;              // 1024
    int lane = tid & 63, wv = tid >> 6;  // 16 waves
    int i = blockIdx.x * 1024 + tid;
    int v = (i < N) ? cnt[i] : 0;
    int incl = v;
    #pragma unroll
    for (int off = 1; off < 64; off <<= 1) {
        int u = __shfl_up(incl, off, 64);
        if (lane >= off) incl += u;
    }
    if (lane == 63) ws[wv] = incl;
    __syncthreads();
    if (wv == 0) {
        int s = (lane < 16) ? ws[lane] : 0;
        #pragma unroll
        for (int off = 1; off < 16; off <<= 1) {
            int u = __shfl_up(s, off, 64);
            if (lane >= off) s += u;
        }
        if (lane < 16) ws[lane] = s;    // inclusive over wave sums
    }
    __syncthreads();
    int add = (wv == 0) ? 0 : ws[wv - 1];
    if (i < N) rowptr[i] = add + incl - v;
    if (tid == 1023) bsum[blockIdx.x] = ws[15];
}

// finalize: re-scan <=64 block sums (first wave), apply; compute dinv.
__global__ void k_scan_c(int* __restrict__ rowptr, const int* __restrict__ bsum,
                         const int* __restrict__ cnt, float* __restrict__ dinv,
                         int* __restrict__ cursor, int N, int E, int nsb) {
    __shared__ int sb[64];
    if (threadIdx.x < 64) {
        int t = threadIdx.x;
        int v = (t < nsb) ? bsum[t] : 0;
        int incl = v;
        #pragma unroll
        for (int off = 1; off < 64; off <<= 1) {
            int u = __shfl_up(incl, off, 64);
            if (t >= off) incl += u;
        }
        sb[t] = incl - v;   // exclusive
    }
    __syncthreads();
    int i = blockIdx.x * blockDim.x + threadIdx.x;
    if (i < N) {
        int v = rowptr[i] + sb[i >> 10];
        rowptr[i] = v;
        cursor[i] = v;
        dinv[i] = rsqrtf(1.0f + (float)cnt[i]);
    }
    if (i == 0) rowptr[N] = E;
}

// Scatter edges into CSR; pack src index + precomputed coef (dinv_s * dinv_d)
__global__ void k_scatter(const int* __restrict__ src, const int* __restrict__ dst,
                          const float* __restrict__ dinv,
                          int* __restrict__ cursor, int2* __restrict__ ecol, int E) {
    int i = blockIdx.x * blockDim.x + threadIdx.x;
    if (i < E) {
        int s = src[i], d = dst[i];
        int p = atomicAdd(&cursor[d], 1);
        float c = dinv[s] * dinv[d];
        ecol[p] = make_int2(s, __float_as_int(c));
    }
}

// ---------------------------------------------------------------------------
// Layer GEMM v3 — 2-tile ping-pong: block owns 128 rows as two 64-row tiles;
// tile 1 stages (global_load_lds DMA) while tile 0 computes. One cold stall
// per 2 tiles. B fragments loaded once (shared by both tiles). XOR-granule
// swizzle on the GLOBAL source (LDS dest linear) + same XOR on ds_read.
// ---------------------------------------------------------------------------
__global__ __launch_bounds__(256) void k_gemm_lf(
    const u16* __restrict__ A, int colOff,
    const u16* __restrict__ Bt, u16* __restrict__ OUTb, int N)
{
    __shared__ u16 sA[2][64 * 128];   // 32 KB ping-pong

    const int tid  = threadIdx.x;
    const int lane = tid & 63;
    const int wave = tid >> 6;
    const int wr   = wave & 1;
    const int wc   = wave >> 1;
    const int quad = lane >> 4;
    const int l15  = lane & 15;
    const int row0 = blockIdx.x * 128;

    // stage helper rounds: 4 x 256 lanes x 16 B = 16 KB per tile
    #define STAGE_A(buf, base)                                                  \
        {                                                                       \
            _Pragma("unroll")                                                   \
            for (int rd = 0; rd < 4; ++rd) {                                    \
                int idx  = rd * 256 + tid;                                      \
                int row  = idx >> 4;                                            \
                int gp   = idx & 15;                                            \
                int gs   = gp ^ (row & 7);                                      \
                int grow = (base) + row; if (grow >= N) grow = N - 1;           \
                const u16* srcp_ = A + (size_t)grow * 512 + colOff + gs * 8;    \
                gload_lds16(srcp_, &sA[buf][(size_t)(rd * 256 + (tid & ~63)) * 8]); \
            }                                                                   \
        }

    STAGE_A(0, row0)

    const u16* pB = Bt + ((size_t)quad * 128 + wc * 64 + l15) * 8;
    bf16x8 bh[4][4];
    #pragma unroll
    for (int kc = 0; kc < 4; ++kc)
        #pragma unroll
        for (int j = 0; j < 4; ++j)
            bh[kc][j] = *(const bf16x8*)(pB + (size_t)kc * 4096 + j * 128);

    const int rL[2] = { wr * 32 + l15, wr * 32 + 16 + l15 };

    #pragma unroll
    for (int t = 0; t < 2; ++t) {
        __syncthreads();                       // sA[t] ready (drains DMA)
        if (t == 0) STAGE_A(1, row0 + 64)      // overlap with tile-0 compute

        bf16x8 ah[4][2];
        #pragma unroll
        for (int kc = 0; kc < 4; ++kc)
            #pragma unroll
            for (int i = 0; i < 2; ++i)
                ah[kc][i] = *(const bf16x8*)&sA[t][rL[i] * 128
                               + (((kc << 2) | quad) ^ (rL[i] & 7)) * 8];

        f32x4 acc[2][4];
        #pragma unroll
        for (int i = 0; i < 2; ++i)
            #pragma unroll
            for (int j = 0; j < 4; ++j)
                #pragma unroll
                for (int r = 0; r < 4; ++r) acc[i][j][r] = 0.f;

        #pragma unroll
        for (int kc = 0; kc < 4; ++kc)
            #pragma unroll
            for (int i = 0; i < 2; ++i)
                #pragma unroll
                for (int j = 0; j < 4; ++j)
                    acc[i][j] = __builtin_amdgcn_mfma_f32_16x16x32_bf16(
                        ah[kc][i], bh[kc][j], acc[i][j], 0, 0, 0);

        #pragma unroll
        for (int i = 0; i < 2; ++i)
            #pragma unroll
            for (int j = 0; j < 4; ++j) {
                int col = wc * 64 + j * 16 + l15;
                #pragma unroll
                for (int r = 0; r < 4; ++r) {
                    int grow = row0 + t * 64 + wr * 32 + i * 16 + quad * 4 + r;
                    if (grow < N)
                        OUTb[(size_t)grow * 128 + col] = f2bf(acc[i][j][r]);
                }
            }
    }
    #undef STAGE_A
}

// ---------------------------------------------------------------------------
// Fused MLP v7 — ping-pong staged A + LDS aliasing (round-12 verified).
// ---------------------------------------------------------------------------
__global__ __launch_bounds__(256) void k_mlp_fused(
    const u16* __restrict__ xcH,
    const u16* __restrict__ B1t, const float* __restrict__ b1,
    const u16* __restrict__ W2h, const u16* __restrict__ W2l,
    const float* __restrict__ b2, float* __restrict__ out, int N)
{
    __shared__ u16 smem[2][64 * 128];  // phase 1: sA ping-pong; phase 2: sZh/sZl

    const int tid  = threadIdx.x;
    const int lane = tid & 63;
    const int wave = tid >> 6;
    const int wr   = wave & 1;   // row half (32 rows)
    const int wc   = wave >> 1;  // col half (64 cols)
    const int quad = lane >> 4;
    const int l15  = lane & 15;
    const int row0 = blockIdx.x * 64;

    #define STAGE_K(buf, kp)                                                    \
        {                                                                       \
            _Pragma("unroll")                                                   \
            for (int rd = 0; rd < 4; ++rd) {                                    \
                int idx  = rd * 256 + tid;                                      \
                int row  = idx >> 4;                                            \
                int gp   = idx & 15;                                            \
                int gs   = gp ^ (row & 7);                                      \
                int grow = row0 + row; if (grow >= N) grow = N - 1;             \
                const u16* srcp_ = xcH + (size_t)grow * 512 + (kp) * 128 + gs * 8; \
                gload_lds16(srcp_, &smem[buf][(size_t)(rd * 256 + (tid & ~63)) * 8]); \
            }                                                                   \
        }

    const u16* pB = B1t + ((size_t)quad * 128 + wc * 64 + l15) * 8;
    const int rL[2] = { wr * 32 + l15, wr * 32 + 16 + l15 };

    f32x4 acc[2][4];
    #pragma unroll
    for (int i = 0; i < 2; ++i)
        #pragma unroll
        for (int j = 0; j < 4; ++j)
            #pragma unroll
            for (int r = 0; r < 4; ++r) acc[i][j][r] = 0.f;

    STAGE_K(0, 0)

    #pragma unroll
    for (int kp = 0; kp < 4; ++kp) {
        __syncthreads();                           // smem[kp&1] ready
        if (kp < 3) STAGE_K((kp + 1) & 1, kp + 1)  // overlap with compute

        bf16x8 bh[4][4];
        #pragma unroll
        for (int c = 0; c < 4; ++c)
            #pragma unroll
            for (int j = 0; j < 4; ++j)
                bh[c][j] = *(const bf16x8*)(pB + (size_t)(kp * 4 + c) * 4096 + j * 128);

        bf16x8 ah[4][2];
        #pragma unroll
        for (int c = 0; c < 4; ++c)
            #pragma unroll
            for (int i = 0; i < 2; ++i)
                ah[c][i] = *(const bf16x8*)&smem[kp & 1][rL[i] * 128
                               + (((c << 2) | quad) ^ (rL[i] & 7)) * 8];

        #pragma unroll
        for (int c = 0; c < 4; ++c)
            #pragma unroll
            for (int i = 0; i < 2; ++i)
                #pragma unroll
                for (int j = 0; j < 4; ++j)
                    acc[i][j] = __builtin_amdgcn_mfma_f32_16x16x32_bf16(
                        ah[c][i], bh[c][j], acc[i][j], 0, 0, 0);
    }
    #undef STAGE_K

    __syncthreads();   // all sA reads done -> safe to reuse smem for sZ
    u16* sZh = smem[0];
    u16* sZl = smem[1];

    // bias + relu + hi/lo split -> LDS (each wave writes its 32x64 tile)
    #pragma unroll
    for (int jt = 0; jt < 4; ++jt) {
        int col = wc * 64 + jt * 16 + l15;
        float bv = b1[col];
        int qq = col >> 3, jj = col & 7;
        #pragma unroll
        for (int i = 0; i < 2; ++i) {
            #pragma unroll
            for (int rr = 0; rr < 4; ++rr) {
                int row = wr * 32 + i * 16 + quad * 4 + rr;
                float v = fmaxf(acc[i][jt][rr] + bv, 0.f);
                u16 h = f2bf(v);
                sZh[(qq * 64 + row) * 8 + jj] = h;
                sZl[(qq * 64 + row) * 8 + jj] = f2bf(v - bf2f(h));
            }
        }
    }
    __syncthreads();

    // phase 2: MLP2 (128->64) + softmax; ALL 4 waves, 16 rows each
    {
        f32x4 oacc[4];
        #pragma unroll
        for (int j = 0; j < 4; ++j)
            #pragma unroll
            for (int r = 0; r < 4; ++r) oacc[j][r] = 0.f;

        #pragma unroll
        for (int kc = 0; kc < 4; ++kc) {
            int qq = kc * 4 + quad;
            bf16x8 zh = *(const bf16x8*)&sZh[(qq * 64 + wave * 16 + l15) * 8];
            bf16x8 zl = *(const bf16x8*)&sZl[(qq * 64 + wave * 16 + l15) * 8];
            #pragma unroll
            for (int jt = 0; jt < 4; ++jt) {
                int n = jt * 16 + l15;
                bf16x8 wh = *(const bf16x8*)&W2h[(qq * 64 + n) * 8];
                bf16x8 wl = *(const bf16x8*)&W2l[(qq * 64 + n) * 8];
                oacc[jt] = __builtin_amdgcn_mfma_f32_16x16x32_bf16(zh, wh, oacc[jt], 0, 0, 0);
                oacc[jt] = __builtin_amdgcn_mfma_f32_16x16x32_bf16(zh, wl, oacc[jt], 0, 0, 0);
                oacc[jt] = __builtin_amdgcn_mfma_f32_16x16x32_bf16(zl, wh, oacc[jt], 0, 0, 0);
            }
        }

        #pragma unroll
        for (int jt = 0; jt < 4; ++jt) {
            float bv = b2[jt * 16 + l15];
            #pragma unroll
            for (int r = 0; r < 4; ++r) oacc[jt][r] += bv;
        }
        #pragma unroll
        for (int r = 0; r < 4; ++r) {
            float m = fmaxf(fmaxf(oacc[0][r], oacc[1][r]), fmaxf(oacc[2][r], oacc[3][r]));
            #pragma unroll
            for (int mask = 8; mask; mask >>= 1) m = fmaxf(m, __shfl_xor(m, mask, 64));
            float p0 = __expf(oacc[0][r] - m);
            float p1 = __expf(oacc[1][r] - m);
            float p2 = __expf(oacc[2][r] - m);
            float p3 = __expf(oacc[3][r] - m);
            float s = p0 + p1 + p2 + p3;
            #pragma unroll
            for (int mask = 8; mask; mask >>= 1) s += __shfl_xor(s, mask, 64);
            float inv = 1.0f / s;
            int grow = row0 + wave * 16 + quad * 4 + r;
            if (grow < N) {
                float* o = out + (size_t)grow * CC + l15;
                o[0]  = p0 * inv;
                o[16] = p1 * inv;
                o[32] = p2 * inv;
                o[48] = p3 * inv;
            }
        }
    }
}

// ---------------------------------------------------------------------------
// Aggregation v2 (symmetric-normalized, self-loop) + bias + LayerNorm + ReLU.
// Node-per-half-wave + SOFTWARE-PIPELINED descriptor loads: batch k+1's
// ecol descriptors are issued between batch k's gather-issue and its consume,
// hiding the ~200cy L2 descriptor latency under the ~500cy gathers. The
// self-row gather (hv) is issued at node start, consumed AFTER the edge loop.
// Next node's rowptr/dinv prefetched before the current edge loop.
// 4 cols/lane, 8B gathers, batch-4, 2 nodes/wave.
// ---------------------------------------------------------------------------
__global__ __launch_bounds__(256, 8) void k_agg_ln(
    const u16* __restrict__ hWb,
    const int* __restrict__ rowptr, const int2* __restrict__ ecol,
    const float* __restrict__ dinv,
    const float* __restrict__ bg, const float* __restrict__ g,
    const float* __restrict__ b,
    u16* __restrict__ outHi, int N)
{
    const int lane = threadIdx.x & 63;
    const int c0   = (lane & 31) << 2;  // 4 owned columns (within half)

    const float4 bgv = *(const float4*)(bg + c0);
    const float4 gv  = *(const float4*)(g + c0);
    const float4 bv  = *(const float4*)(b + c0);

    const int nslots = gridDim.x * 8;   // 2 nodes per wave, 4 waves per block
    int wid = blockIdx.x * 8 + ((threadIdx.x >> 6) << 1) + (lane >> 5);
    if (wid >= N) return;

    // descriptors for the first node
    int e0 = rowptr[wid];
    int e1 = rowptr[wid + 1];
    float di = dinv[wid];

    while (true) {
        // prefetch NEXT node's descriptors (consumed ~one edge-loop later)
        const int widn = wid + nslots;
        int e0n = 0, e1n = 0;
        float din = 0.f;
        if (widn < N) {
            e0n = rowptr[widn];
            e1n = rowptr[widn + 1];
            din = dinv[widn];
        }

        // issue self-row gather early; consumed after the edge loop
        uint2 hv = *(const uint2*)(hWb + (size_t)wid * HH + c0);

        float a0 = 0.f, a1 = 0.f, a2 = 0.f, a3 = 0.f;
        float q0 = 0.f, q1 = 0.f, q2 = 0.f, q3 = 0.f;

        const int m = e1 - e0;
        const int2* ep = ecol + e0;

        int k = 0;
        if (m >= 4) {
            // pipelined batch-4 loop: next batch's descriptors issued
            // between this batch's gather-issue and its consume.
            int2 p0 = ep[0], p1 = ep[1], p2 = ep[2], p3 = ep[3];
            while (true) {
                uint2 v0 = *(const uint2*)(hWb + (size_t)p0.x * HH + c0);
                uint2 v1 = *(const uint2*)(hWb + (size_t)p1.x * HH + c0);
                uint2 v2 = *(const uint2*)(hWb + (size_t)p2.x * HH + c0);
                uint2 v3 = *(const uint2*)(hWb + (size_t)p3.x * HH + c0);
                float c0f = __int_as_float(p0.y);
                float c1f = __int_as_float(p1.y);
                float c2f = __int_as_float(p2.y);
                float c3f = __int_as_float(p3.y);
                k += 4;
                const bool more = (k + 4 <= m);
                int2 n0 = p0, n1 = p1, n2 = p2, n3 = p3;
                if (more) {                 // issue BEFORE consuming v0..v3
                    n0 = ep[k]; n1 = ep[k + 1]; n2 = ep[k + 2]; n3 = ep[k + 3];
                }
                a0 += bf2f((u16)v0.x) * c0f;  a1 += bf2f((u16)(v0.x >> 16)) * c0f;
                a2 += bf2f((u16)v0.y) * c0f;  a3 += bf2f((u16)(v0.y >> 16)) * c0f;
                q0 += bf2f((u16)v1.x) * c1f;  q1 += bf2f((u16)(v1.x >> 16)) * c1f;
                q2 += bf2f((u16)v1.y) * c1f;  q3 += bf2f((u16)(v1.y >> 16)) * c1f;
                a0 += bf2f((u16)v2.x) * c2f;  a1 += bf2f((u16)(v2.x >> 16)) * c2f;
                a2 += bf2f((u16)v2.y) * c2f;  a3 += bf2f((u16)(v2.y >> 16)) * c2f;
                q0 += bf2f((u16)v3.x) * c3f;  q1 += bf2f((u16)(v3.x >> 16)) * c3f;
                q2 += bf2f((u16)v3.y) * c3f;  q3 += bf2f((u16)(v3.y >> 16)) * c3f;
                if (!more) break;
                p0 = n0; p1 = n1; p2 = n2; p3 = n3;
            }
        }
        if (k < m) {                     // tail <=3, issue together
            int2 p0 = ep[k];
            int2 p1 = (k + 1 < m) ? ep[k + 1] : p0;
            int2 p2 = (k + 2 < m) ? ep[k + 2] : p0;
            uint2 v0 = *(const uint2*)(hWb + (size_t)p0.x * HH + c0);
            uint2 v1 = *(const uint2*)(hWb + (size_t)p1.x * HH + c0);
            uint2 v2 = *(const uint2*)(hWb + (size_t)p2.x * HH + c0);
            float cc0 = __int_as_float(p0.y);
            float cc1 = (k + 1 < m) ? __int_as_float(p1.y) : 0.f;
            float cc2 = (k + 2 < m) ? __int_as_float(p2.y) : 0.f;
            a0 += bf2f((u16)v0.x) * cc0;  a1 += bf2f((u16)(v0.x >> 16)) * cc0;
            a2 += bf2f((u16)v0.y) * cc0;  a3 += bf2f((u16)(v0.y >> 16)) * cc0;
            q0 += bf2f((u16)v1.x) * cc1;  q1 += bf2f((u16)(v1.x >> 16)) * cc1;
            q2 += bf2f((u16)v1.y) * cc1;  q3 += bf2f((u16)(v1.y >> 16)) * cc1;
            a0 += bf2f((u16)v2.x) * cc2;  a1 += bf2f((u16)(v2.x >> 16)) * cc2;
            a2 += bf2f((u16)v2.y) * cc2;  a3 += bf2f((u16)(v2.y >> 16)) * cc2;
        }

        // fold self-loop (hv gather issued at node start) + bias
        const float sc = di * di;
        a0 += q0 + bf2f((u16)hv.x) * sc;
        a1 += q1 + bf2f((u16)(hv.x >> 16)) * sc;
        a2 += q2 + bf2f((u16)hv.y) * sc;
        a3 += q3 + bf2f((u16)(hv.y >> 16)) * sc;
        a0 += bgv.x; a1 += bgv.y; a2 += bgv.z; a3 += bgv.w;

        // LayerNorm over 128 cols (reduce within the 32-lane half)
        float ssum = (a0 + a1) + (a2 + a3);
        #pragma unroll
        for (int off = 16; off; off >>= 1) ssum += __shfl_xor(ssum, off, 64);
        float mu = ssum * (1.0f / 128.0f);
        float d0 = a0 - mu, d1 = a1 - mu, d2 = a2 - mu, d3 = a3 - mu;
        float vsum = (d0 * d0 + d1 * d1) + (d2 * d2 + d3 * d3);
        #pragma unroll
        for (int off = 16; off; off >>= 1) vsum += __shfl_xor(vsum, off, 64);
        float rstd = rsqrtf(vsum * (1.0f / 128.0f) + LN_EPS);

        float o0 = fmaxf(gv.x * d0 * rstd + bv.x, 0.f);
        float o1 = fmaxf(gv.y * d1 * rstd + bv.y, 0.f);
        float o2 = fmaxf(gv.z * d2 * rstd + bv.z, 0.f);
        float o3 = fmaxf(gv.w * d3 * rstd + bv.w, 0.f);
        uint2 o;
        o.x = (u32)f2bf(o0) | ((u32)f2bf(o1) << 16);
        o.y = (u32)f2bf(o2) | ((u32)f2bf(o3) << 16);
        *(uint2*)&outHi[(size_t)wid * 512 + c0] = o;

        if (widn >= N) break;
        wid = widn; e0 = e0n; e1 = e1n; di = din;
    }
}

// ---------------------------------------------------------------------------
// Host launcher
// ---------------------------------------------------------------------------
extern "C" void kernel_launch(void* const* d_in, const int* in_sizes, int n_in,
                              void* d_out, int out_size, void* d_ws, size_t ws_size,
                              hipStream_t stream) {
    const float* x   = (const float*)d_in[0];
    const int*   ei  = (const int*)  d_in[1];
    const float* Wg  = (const float*)d_in[2];
    const float* bg  = (const float*)d_in[3];
    const float* lng = (const float*)d_in[4];
    const float* lnb = (const float*)d_in[5];
    const float* W1  = (const float*)d_in[6];
    const float* b1  = (const float*)d_in[7];
    const float* W2  = (const float*)d_in[8];
    const float* b2  = (const float*)d_in[9];
    float* out = (float*)d_out;

    const int N = in_sizes[0] / D;
    const int E = in_sizes[1] / 2;
    const int* srcp = ei;
    const int* dstp = ei + E;

    char* ws = (char*)d_ws;
    size_t off = 0;
    auto alloc = [&](size_t bytes) -> void* {
        void* p = ws + off;
        off += (bytes + 511) & ~(size_t)511;
        return p;
    };
    int*   cnt    = (int*)  alloc((size_t)N * 4);
    int*   rowptr = (int*)  alloc((size_t)(N + 1) * 4);
    int*   cursor = (int*)  alloc((size_t)N * 4);
    int*   bsum   = (int*)  alloc(64 * 4);
    int2*  ecol   = (int2*) alloc((size_t)E * 8);
    float* dinv   = (float*)alloc((size_t)N * 4);
    u16*   hWb    = (u16*)  alloc((size_t)N * HH * 2);       // layer GEMM bf16 out
    u16*   xcH    = (u16*)  alloc((size_t)N * 512 * 2);      // [x|f1|f2|f3] bf16
    u16*   WgtH   = (u16*)  alloc((size_t)NLAYERS * D * HH * 2);
    u16*   W1tH   = (u16*)  alloc((size_t)(D + NLAYERS * HH) * HH * 2);
    u16*   W2tH   = (u16*)  alloc((size_t)HH * CC * 2);
    u16*   W2tL   = (u16*)  alloc((size_t)HH * CC * 2);

    const int B = 256;
    const int gE = (E + B - 1) / B;
    const int nsb = (N + 1023) / 1024;

    // zero degree counts (stream-ordered; graph-capture legal)
    hipMemsetAsync(cnt, 0, (size_t)N * 4, stream);

    // fused prep: x->bf16 (x4) + all weight tilings + edge counting
    const int prepTotal = N * (D / 4) + NLAYERS * D * HH
                        + (D + NLAYERS * HH) * HH + HH * CC + E;
    k_prep<<<(prepTotal + B - 1) / B, B, 0, stream>>>(x, xcH, Wg, WgtH, W1, W1tH,
                                                      W2, W2tH, W2tL, dstp, cnt, N, E);
    k_scan_a<<<nsb, 1024, 0, stream>>>(cnt, rowptr, bsum, N);
    k_scan_c<<<(N + B - 1) / B, B, 0, stream>>>(rowptr, bsum, cnt, dinv, cursor, N, E, nsb);
    k_scatter<<<gE, B, 0, stream>>>(srcp, dstp, dinv, cursor, ecol, E);

    const int gemmBlocks = (N + 127) / 128;   // 2-tile blocks
    const int mlpBlocks  = (N + 63) / 64;
    const int aggBlocks  = 2048;              // persistent: 8192 waves x 2 nodes

    for (int l = 0; l < NLAYERS; ++l) {
        // hWb = bf16(h @ Wg[l])  (bias added after aggregation)
        k_gemm_lf<<<gemmBlocks, B, 0, stream>>>(xcH, l * HH,
                                                WgtH + (size_t)l * D * HH, hWb, N);
        k_agg_ln<<<aggBlocks, B, 0, stream>>>(hWb, rowptr, ecol, dinv,
                                              bg + (size_t)l * HH,
                                              lng + (size_t)l * HH,
                                              lnb + (size_t)l * HH,
                                              xcH + (size_t)(l + 1) * HH, N);
    }

    // out = softmax(relu([x|f1|f2|f3] @ W1 + b1) @ W2 + b2), fused
    k_mlp_fused<<<mlpBlocks, B, 0, stream>>>(xcH, W1tH, b1,
                                             W2tH, W2tL, b2, out, N);
}

// Round 14
// 289.076 us; speedup vs baseline: 1.1625x; 1.1625x over previous
//
#include <hip/hip_runtime.h>
#include <math.h>

// Problem constants (shapes fixed by the reference)
#define D 128
#define HH 128
#define CC 64
#define NLAYERS 3
#define LN_EPS 1e-5f

typedef __attribute__((ext_vector_type(8))) short bf16x8;
typedef __attribute__((ext_vector_type(4))) float f32x4;
typedef unsigned short u16;
typedef unsigned int u32;

// round-to-nearest-even fp32 -> bf16 bits
__device__ __forceinline__ u16 f2bf(float f) {
    u32 u = __float_as_uint(f);
    u32 r = u + 0x7FFFu + ((u >> 16) & 1u);
    return (u16)(r >> 16);
}
__device__ __forceinline__ float bf2f(u16 h) {
    return __uint_as_float(((u32)h) << 16);
}

// async global->LDS DMA, 16 B per lane (dest = wave-uniform base + lane*16)
__device__ __forceinline__ void gload_lds16(const void* g, void* l) {
    __builtin_amdgcn_global_load_lds(
        (const __attribute__((address_space(1))) void*)g,
        (__attribute__((address_space(3))) void*)l, 16, 0, 0);
}

// ---------------------------------------------------------------------------
// k_prep: fused setup — x->bf16 (float4) + tile Wg/W1/W2 + edge counting
// (cnt zeroed by hipMemsetAsync before this launch).
// Tiled layout: [kc][q][n][j], k = kc*32 + q*8 + j.
// ---------------------------------------------------------------------------
__global__ void k_prep(const float* __restrict__ x, u16* __restrict__ xh,
                       const float* __restrict__ Wg, u16* __restrict__ WgtH,
                       const float* __restrict__ W1, u16* __restrict__ W1tH,
                       const float* __restrict__ W2, u16* __restrict__ W2tH,
                       u16* __restrict__ W2tL,
                       const int* __restrict__ dst, int* __restrict__ cnt,
                       int N, int E)
{
    int i = blockIdx.x * blockDim.x + threadIdx.x;
    // seg 0: x -> bf16 hi, 4 elements per thread (float4 load, ushort4 store)
    int nx4 = N * (D / 4);
    if (i < nx4) {
        float4 v = *(const float4*)(x + (size_t)i * 4);
        int row = i >> 5, c = (i & 31) << 2;
        ushort4 o;
        o.x = f2bf(v.x); o.y = f2bf(v.y); o.z = f2bf(v.z); o.w = f2bf(v.w);
        *(ushort4*)&xh[(size_t)row * 512 + c] = o;
        return;
    }
    i -= nx4;
    // seg 1: Wg (3 stacked 128x128 matrices; layout linear in kc)
    if (i < NLAYERS * D * HH) {
        int k = i >> 7, n = i & 127;
        int kc = k >> 5, q = (k >> 3) & 3, j = k & 7;
        WgtH[(((kc * 4 + q) << 7) + n) * 8 + j] = f2bf(Wg[i]);
        return;
    }
    i -= NLAYERS * D * HH;
    // seg 2: W1 (512x128)
    if (i < (D + NLAYERS * HH) * HH) {
        int k = i >> 7, n = i & 127;
        int kc = k >> 5, q = (k >> 3) & 3, j = k & 7;
        W1tH[(((kc * 4 + q) << 7) + n) * 8 + j] = f2bf(W1[i]);
        return;
    }
    i -= (D + NLAYERS * HH) * HH;
    // seg 3: W2 (128x64), hi + lo (split-3 in mlp phase 2)
    if (i < HH * CC) {
        int k = i >> 6, n = i & 63;
        int kc = k >> 5, q = (k >> 3) & 3, j = k & 7;
        float v = W2[i];
        u16 h = f2bf(v);
        int o = (((kc * 4 + q) << 6) + n) * 8 + j;
        W2tH[o] = h;
        W2tL[o] = f2bf(v - bf2f(h));
        return;
    }
    i -= HH * CC;
    // seg 4: edge degree count (cnt pre-zeroed by hipMemsetAsync)
    if (i < E) atomicAdd(&cnt[dst[i]], 1);
}

// ---------------------------------------------------------------------------
// CSR build: scan_a -> scan_c -> scatter. Separate small launches:
// grid.sync() on MI355X costs ~100 µs/barrier (round-2: fused coop = 527 µs).
// ---------------------------------------------------------------------------

// shuffle-based block scan: 2 barriers
__global__ void k_scan_a(const int* __restrict__ cnt, int* __restrict__ rowptr,
                         int* __restrict__ bsum, int N) {
    __shared__ int ws[16];
    int tid  = threadIdx.x;              // 1024
    int lane = tid & 63, wv = tid >> 6;  // 16 waves
    int i = blockIdx.x * 1024 + tid;
    int v = (i < N) ? cnt[i] : 0;
    int incl = v;
    #pragma unroll
    for (int off = 1; off < 64; off <<= 1) {
        int u = __shfl_up(incl, off, 64);
        if (lane >= off) incl += u;
    }
    if (lane == 63) ws[wv] = incl;
    __syncthreads();
    if (wv == 0) {
        int s = (lane < 16) ? ws[lane] : 0;
        #pragma unroll
        for (int off = 1; off < 16; off <<= 1) {
            int u = __shfl_up(s, off, 64);
            if (lane >= off) s += u;
        }
        if (lane < 16) ws[lane] = s;    // inclusive over wave sums
    }
    __syncthreads();
    int add = (wv == 0) ? 0 : ws[wv - 1];
    if (i < N) rowptr[i] = add + incl - v;
    if (tid == 1023) bsum[blockIdx.x] = ws[15];
}

// finalize: re-scan <=64 block sums (first wave), apply; compute dinv.
__global__ void k_scan_c(int* __restrict__ rowptr, const int* __restrict__ bsum,
                         const int* __restrict__ cnt, float* __restrict__ dinv,
                         int* __restrict__ cursor, int N, int E, int nsb) {
    __shared__ int sb[64];
    if (threadIdx.x < 64) {
        int t = threadIdx.x;
        int v = (t < nsb) ? bsum[t] : 0;
        int incl = v;
        #pragma unroll
        for (int off = 1; off < 64; off <<= 1) {
            int u = __shfl_up(incl, off, 64);
            if (t >= off) incl += u;
        }
        sb[t] = incl - v;   // exclusive
    }
    __syncthreads();
    int i = blockIdx.x * blockDim.x + threadIdx.x;
    if (i < N) {
        int v = rowptr[i] + sb[i >> 10];
        rowptr[i] = v;
        cursor[i] = v;
        dinv[i] = rsqrtf(1.0f + (float)cnt[i]);
    }
    if (i == 0) rowptr[N] = E;
}

// Scatter edges into CSR; pack src index + precomputed coef (dinv_s * dinv_d)
__global__ void k_scatter(const int* __restrict__ src, const int* __restrict__ dst,
                          const float* __restrict__ dinv,
                          int* __restrict__ cursor, int2* __restrict__ ecol, int E) {
    int i = blockIdx.x * blockDim.x + threadIdx.x;
    if (i < E) {
        int s = src[i], d = dst[i];
        int p = atomicAdd(&cursor[d], 1);
        float c = dinv[s] * dinv[d];
        ecol[p] = make_int2(s, __float_as_int(c));
    }
}

// ---------------------------------------------------------------------------
// Layer GEMM v3 — 2-tile ping-pong: block owns 128 rows as two 64-row tiles;
// tile 1 stages (global_load_lds DMA) while tile 0 computes. One cold stall
// per 2 tiles. B fragments loaded once (shared by both tiles). XOR-granule
// swizzle on the GLOBAL source (LDS dest linear) + same XOR on ds_read.
// ---------------------------------------------------------------------------
__global__ __launch_bounds__(256) void k_gemm_lf(
    const u16* __restrict__ A, int colOff,
    const u16* __restrict__ Bt, u16* __restrict__ OUTb, int N)
{
    __shared__ u16 sA[2][64 * 128];   // 32 KB ping-pong

    const int tid  = threadIdx.x;
    const int lane = tid & 63;
    const int wave = tid >> 6;
    const int wr   = wave & 1;
    const int wc   = wave >> 1;
    const int quad = lane >> 4;
    const int l15  = lane & 15;
    const int row0 = blockIdx.x * 128;

    // stage helper rounds: 4 x 256 lanes x 16 B = 16 KB per tile
    #define STAGE_A(buf, base)                                                  \
        {                                                                       \
            _Pragma("unroll")                                                   \
            for (int rd = 0; rd < 4; ++rd) {                                    \
                int idx  = rd * 256 + tid;                                      \
                int row  = idx >> 4;                                            \
                int gp   = idx & 15;                                            \
                int gs   = gp ^ (row & 7);                                      \
                int grow = (base) + row; if (grow >= N) grow = N - 1;           \
                const u16* srcp_ = A + (size_t)grow * 512 + colOff + gs * 8;    \
                gload_lds16(srcp_, &sA[buf][(size_t)(rd * 256 + (tid & ~63)) * 8]); \
            }                                                                   \
        }

    STAGE_A(0, row0)

    const u16* pB = Bt + ((size_t)quad * 128 + wc * 64 + l15) * 8;
    bf16x8 bh[4][4];
    #pragma unroll
    for (int kc = 0; kc < 4; ++kc)
        #pragma unroll
        for (int j = 0; j < 4; ++j)
            bh[kc][j] = *(const bf16x8*)(pB + (size_t)kc * 4096 + j * 128);

    const int rL[2] = { wr * 32 + l15, wr * 32 + 16 + l15 };

    #pragma unroll
    for (int t = 0; t < 2; ++t) {
        __syncthreads();                       // sA[t] ready (drains DMA)
        if (t == 0) STAGE_A(1, row0 + 64)      // overlap with tile-0 compute

        bf16x8 ah[4][2];
        #pragma unroll
        for (int kc = 0; kc < 4; ++kc)
            #pragma unroll
            for (int i = 0; i < 2; ++i)
                ah[kc][i] = *(const bf16x8*)&sA[t][rL[i] * 128
                               + (((kc << 2) | quad) ^ (rL[i] & 7)) * 8];

        f32x4 acc[2][4];
        #pragma unroll
        for (int i = 0; i < 2; ++i)
            #pragma unroll
            for (int j = 0; j < 4; ++j)
                #pragma unroll
                for (int r = 0; r < 4; ++r) acc[i][j][r] = 0.f;

        #pragma unroll
        for (int kc = 0; kc < 4; ++kc)
            #pragma unroll
            for (int i = 0; i < 2; ++i)
                #pragma unroll
                for (int j = 0; j < 4; ++j)
                    acc[i][j] = __builtin_amdgcn_mfma_f32_16x16x32_bf16(
                        ah[kc][i], bh[kc][j], acc[i][j], 0, 0, 0);

        #pragma unroll
        for (int i = 0; i < 2; ++i)
            #pragma unroll
            for (int j = 0; j < 4; ++j) {
                int col = wc * 64 + j * 16 + l15;
                #pragma unroll
                for (int r = 0; r < 4; ++r) {
                    int grow = row0 + t * 64 + wr * 32 + i * 16 + quad * 4 + r;
                    if (grow < N)
                        OUTb[(size_t)grow * 128 + col] = f2bf(acc[i][j][r]);
                }
            }
    }
    #undef STAGE_A
}

// ---------------------------------------------------------------------------
// Fused MLP v7 — ping-pong staged A + LDS aliasing (round-12 verified).
// ---------------------------------------------------------------------------
__global__ __launch_bounds__(256) void k_mlp_fused(
    const u16* __restrict__ xcH,
    const u16* __restrict__ B1t, const float* __restrict__ b1,
    const u16* __restrict__ W2h, const u16* __restrict__ W2l,
    const float* __restrict__ b2, float* __restrict__ out, int N)
{
    __shared__ u16 smem[2][64 * 128];  // phase 1: sA ping-pong; phase 2: sZh/sZl

    const int tid  = threadIdx.x;
    const int lane = tid & 63;
    const int wave = tid >> 6;
    const int wr   = wave & 1;   // row half (32 rows)
    const int wc   = wave >> 1;  // col half (64 cols)
    const int quad = lane >> 4;
    const int l15  = lane & 15;
    const int row0 = blockIdx.x * 64;

    #define STAGE_K(buf, kp)                                                    \
        {                                                                       \
            _Pragma("unroll")                                                   \
            for (int rd = 0; rd < 4; ++rd) {                                    \
                int idx  = rd * 256 + tid;                                      \
                int row  = idx >> 4;                                            \
                int gp   = idx & 15;                                            \
                int gs   = gp ^ (row & 7);                                      \
                int grow = row0 + row; if (grow >= N) grow = N - 1;             \
                const u16* srcp_ = xcH + (size_t)grow * 512 + (kp) * 128 + gs * 8; \
                gload_lds16(srcp_, &smem[buf][(size_t)(rd * 256 + (tid & ~63)) * 8]); \
            }                                                                   \
        }

    const u16* pB = B1t + ((size_t)quad * 128 + wc * 64 + l15) * 8;
    const int rL[2] = { wr * 32 + l15, wr * 32 + 16 + l15 };

    f32x4 acc[2][4];
    #pragma unroll
    for (int i = 0; i < 2; ++i)
        #pragma unroll
        for (int j = 0; j < 4; ++j)
            #pragma unroll
            for (int r = 0; r < 4; ++r) acc[i][j][r] = 0.f;

    STAGE_K(0, 0)

    #pragma unroll
    for (int kp = 0; kp < 4; ++kp) {
        __syncthreads();                           // smem[kp&1] ready
        if (kp < 3) STAGE_K((kp + 1) & 1, kp + 1)  // overlap with compute

        bf16x8 bh[4][4];
        #pragma unroll
        for (int c = 0; c < 4; ++c)
            #pragma unroll
            for (int j = 0; j < 4; ++j)
                bh[c][j] = *(const bf16x8*)(pB + (size_t)(kp * 4 + c) * 4096 + j * 128);

        bf16x8 ah[4][2];
        #pragma unroll
        for (int c = 0; c < 4; ++c)
            #pragma unroll
            for (int i = 0; i < 2; ++i)
                ah[c][i] = *(const bf16x8*)&smem[kp & 1][rL[i] * 128
                               + (((c << 2) | quad) ^ (rL[i] & 7)) * 8];

        #pragma unroll
        for (int c = 0; c < 4; ++c)
            #pragma unroll
            for (int i = 0; i < 2; ++i)
                #pragma unroll
                for (int j = 0; j < 4; ++j)
                    acc[i][j] = __builtin_amdgcn_mfma_f32_16x16x32_bf16(
                        ah[c][i], bh[c][j], acc[i][j], 0, 0, 0);
    }
    #undef STAGE_K

    __syncthreads();   // all sA reads done -> safe to reuse smem for sZ
    u16* sZh = smem[0];
    u16* sZl = smem[1];

    // bias + relu + hi/lo split -> LDS (each wave writes its 32x64 tile)
    #pragma unroll
    for (int jt = 0; jt < 4; ++jt) {
        int col = wc * 64 + jt * 16 + l15;
        float bv = b1[col];
        int qq = col >> 3, jj = col & 7;
        #pragma unroll
        for (int i = 0; i < 2; ++i) {
            #pragma unroll
            for (int rr = 0; rr < 4; ++rr) {
                int row = wr * 32 + i * 16 + quad * 4 + rr;
                float v = fmaxf(acc[i][jt][rr] + bv, 0.f);
                u16 h = f2bf(v);
                sZh[(qq * 64 + row) * 8 + jj] = h;
                sZl[(qq * 64 + row) * 8 + jj] = f2bf(v - bf2f(h));
            }
        }
    }
    __syncthreads();

    // phase 2: MLP2 (128->64) + softmax; ALL 4 waves, 16 rows each
    {
        f32x4 oacc[4];
        #pragma unroll
        for (int j = 0; j < 4; ++j)
            #pragma unroll
            for (int r = 0; r < 4; ++r) oacc[j][r] = 0.f;

        #pragma unroll
        for (int kc = 0; kc < 4; ++kc) {
            int qq = kc * 4 + quad;
            bf16x8 zh = *(const bf16x8*)&sZh[(qq * 64 + wave * 16 + l15) * 8];
            bf16x8 zl = *(const bf16x8*)&sZl[(qq * 64 + wave * 16 + l15) * 8];
            #pragma unroll
            for (int jt = 0; jt < 4; ++jt) {
                int n = jt * 16 + l15;
                bf16x8 wh = *(const bf16x8*)&W2h[(qq * 64 + n) * 8];
                bf16x8 wl = *(const bf16x8*)&W2l[(qq * 64 + n) * 8];
                oacc[jt] = __builtin_amdgcn_mfma_f32_16x16x32_bf16(zh, wh, oacc[jt], 0, 0, 0);
                oacc[jt] = __builtin_amdgcn_mfma_f32_16x16x32_bf16(zh, wl, oacc[jt], 0, 0, 0);
                oacc[jt] = __builtin_amdgcn_mfma_f32_16x16x32_bf16(zl, wh, oacc[jt], 0, 0, 0);
            }
        }

        #pragma unroll
        for (int jt = 0; jt < 4; ++jt) {
            float bv = b2[jt * 16 + l15];
            #pragma unroll
            for (int r = 0; r < 4; ++r) oacc[jt][r] += bv;
        }
        #pragma unroll
        for (int r = 0; r < 4; ++r) {
            float m = fmaxf(fmaxf(oacc[0][r], oacc[1][r]), fmaxf(oacc[2][r], oacc[3][r]));
            #pragma unroll
            for (int mask = 8; mask; mask >>= 1) m = fmaxf(m, __shfl_xor(m, mask, 64));
            float p0 = __expf(oacc[0][r] - m);
            float p1 = __expf(oacc[1][r] - m);
            float p2 = __expf(oacc[2][r] - m);
            float p3 = __expf(oacc[3][r] - m);
            float s = p0 + p1 + p2 + p3;
            #pragma unroll
            for (int mask = 8; mask; mask >>= 1) s += __shfl_xor(s, mask, 64);
            float inv = 1.0f / s;
            int grow = row0 + wave * 16 + quad * 4 + r;
            if (grow < N) {
                float* o = out + (size_t)grow * CC + l15;
                o[0]  = p0 * inv;
                o[16] = p1 * inv;
                o[32] = p2 * inv;
                o[48] = p3 * inv;
            }
        }
    }
}

// ---------------------------------------------------------------------------
// Aggregation (symmetric-normalized, self-loop) + bias + LayerNorm + ReLU.
// EXACT round-6-verified version (part of the 289.3 µs best run). Round 13
// proved the hand-pipelined rotation REGRESSES (~+10 µs/dispatch): the
// compiler already overlaps descriptor+gather issue in this simple loop, and
// cross-wave TLP (57% occupancy) hides the rest. Node-per-half-wave,
// 4 cols/lane, 8B gathers, batch-4, 2 nodes/wave.
// ---------------------------------------------------------------------------
__global__ __launch_bounds__(256, 8) void k_agg_ln(
    const u16* __restrict__ hWb,
    const int* __restrict__ rowptr, const int2* __restrict__ ecol,
    const float* __restrict__ dinv,
    const float* __restrict__ bg, const float* __restrict__ g,
    const float* __restrict__ b,
    u16* __restrict__ outHi, int N)
{
    const int lane = threadIdx.x & 63;
    const int c0   = (lane & 31) << 2;  // 4 owned columns (within half)

    const float4 bgv = *(const float4*)(bg + c0);
    const float4 gv  = *(const float4*)(g + c0);
    const float4 bv  = *(const float4*)(b + c0);

    const int nslots = gridDim.x * 8;   // 2 nodes per wave, 4 waves per block
    for (int wid = blockIdx.x * 8 + ((threadIdx.x >> 6) << 1) + (lane >> 5);
         wid < N; wid += nslots) {
        float di = dinv[wid];
        float sc = di * di;

        // self-loop term
        uint2 hv = *(const uint2*)(hWb + (size_t)wid * HH + c0);
        float a0 = bf2f((u16)hv.x) * sc;
        float a1 = bf2f((u16)(hv.x >> 16)) * sc;
        float a2 = bf2f((u16)hv.y) * sc;
        float a3 = bf2f((u16)(hv.y >> 16)) * sc;
        float q0 = 0.f, q1 = 0.f, q2 = 0.f, q3 = 0.f;

        int e0 = rowptr[wid];
        int m  = rowptr[wid + 1] - e0;
        const int2* ep = ecol + e0;

        int k = 0;
        for (; k + 4 <= m; k += 4) {     // 4 independent gathers in flight
            int2 p[4];
            uint2 v[4];
            #pragma unroll
            for (int t = 0; t < 4; ++t) p[t] = ep[k + t];
            #pragma unroll
            for (int t = 0; t < 4; ++t)
                v[t] = *(const uint2*)(hWb + (size_t)p[t].x * HH + c0);
            #pragma unroll
            for (int t = 0; t < 4; ++t) {
                float c = __int_as_float(p[t].y);
                float x0 = bf2f((u16)v[t].x) * c;
                float x1 = bf2f((u16)(v[t].x >> 16)) * c;
                float x2 = bf2f((u16)v[t].y) * c;
                float x3 = bf2f((u16)(v[t].y >> 16)) * c;
                if (t & 1) { q0 += x0; q1 += x1; q2 += x2; q3 += x3; }
                else       { a0 += x0; a1 += x1; a2 += x2; a3 += x3; }
            }
        }
        if (k < m) {                     // tail <=3, issue together
            int2 p0 = ep[k];
            int2 p1 = (k + 1 < m) ? ep[k + 1] : p0;
            int2 p2 = (k + 2 < m) ? ep[k + 2] : p0;
            uint2 v0 = *(const uint2*)(hWb + (size_t)p0.x * HH + c0);
            uint2 v1 = *(const uint2*)(hWb + (size_t)p1.x * HH + c0);
            uint2 v2 = *(const uint2*)(hWb + (size_t)p2.x * HH + c0);
            float cc0 = __int_as_float(p0.y);
            float cc1 = (k + 1 < m) ? __int_as_float(p1.y) : 0.f;
            float cc2 = (k + 2 < m) ? __int_as_float(p2.y) : 0.f;
            a0 += bf2f((u16)v0.x) * cc0;  a1 += bf2f((u16)(v0.x >> 16)) * cc0;
            a2 += bf2f((u16)v0.y) * cc0;  a3 += bf2f((u16)(v0.y >> 16)) * cc0;
            q0 += bf2f((u16)v1.x) * cc1;  q1 += bf2f((u16)(v1.x >> 16)) * cc1;
            q2 += bf2f((u16)v1.y) * cc1;  q3 += bf2f((u16)(v1.y >> 16)) * cc1;
            a0 += bf2f((u16)v2.x) * cc2;  a1 += bf2f((u16)(v2.x >> 16)) * cc2;
            a2 += bf2f((u16)v2.y) * cc2;  a3 += bf2f((u16)(v2.y >> 16)) * cc2;
        }
        a0 += q0; a1 += q1; a2 += q2; a3 += q3;
        a0 += bgv.x; a1 += bgv.y; a2 += bgv.z; a3 += bgv.w;

        // LayerNorm over 128 cols (reduce within the 32-lane half)
        float ssum = (a0 + a1) + (a2 + a3);
        #pragma unroll
        for (int off = 16; off; off >>= 1) ssum += __shfl_xor(ssum, off, 64);
        float mu = ssum * (1.0f / 128.0f);
        float d0 = a0 - mu, d1 = a1 - mu, d2 = a2 - mu, d3 = a3 - mu;
        float vsum = (d0 * d0 + d1 * d1) + (d2 * d2 + d3 * d3);
        #pragma unroll
        for (int off = 16; off; off >>= 1) vsum += __shfl_xor(vsum, off, 64);
        float rstd = rsqrtf(vsum * (1.0f / 128.0f) + LN_EPS);

        float o0 = fmaxf(gv.x * d0 * rstd + bv.x, 0.f);
        float o1 = fmaxf(gv.y * d1 * rstd + bv.y, 0.f);
        float o2 = fmaxf(gv.z * d2 * rstd + bv.z, 0.f);
        float o3 = fmaxf(gv.w * d3 * rstd + bv.w, 0.f);
        uint2 o;
        o.x = (u32)f2bf(o0) | ((u32)f2bf(o1) << 16);
        o.y = (u32)f2bf(o2) | ((u32)f2bf(o3) << 16);
        *(uint2*)&outHi[(size_t)wid * 512 + c0] = o;
    }
}

// ---------------------------------------------------------------------------
// Host launcher
// ---------------------------------------------------------------------------
extern "C" void kernel_launch(void* const* d_in, const int* in_sizes, int n_in,
                              void* d_out, int out_size, void* d_ws, size_t ws_size,
                              hipStream_t stream) {
    const float* x   = (const float*)d_in[0];
    const int*   ei  = (const int*)  d_in[1];
    const float* Wg  = (const float*)d_in[2];
    const float* bg  = (const float*)d_in[3];
    const float* lng = (const float*)d_in[4];
    const float* lnb = (const float*)d_in[5];
    const float* W1  = (const float*)d_in[6];
    const float* b1  = (const float*)d_in[7];
    const float* W2  = (const float*)d_in[8];
    const float* b2  = (const float*)d_in[9];
    float* out = (float*)d_out;

    const int N = in_sizes[0] / D;
    const int E = in_sizes[1] / 2;
    const int* srcp = ei;
    const int* dstp = ei + E;

    char* ws = (char*)d_ws;
    size_t off = 0;
    auto alloc = [&](size_t bytes) -> void* {
        void* p = ws + off;
        off += (bytes + 511) & ~(size_t)511;
        return p;
    };
    int*   cnt    = (int*)  alloc((size_t)N * 4);
    int*   rowptr = (int*)  alloc((size_t)(N + 1) * 4);
    int*   cursor = (int*)  alloc((size_t)N * 4);
    int*   bsum   = (int*)  alloc(64 * 4);
    int2*  ecol   = (int2*) alloc((size_t)E * 8);
    float* dinv   = (float*)alloc((size_t)N * 4);
    u16*   hWb    = (u16*)  alloc((size_t)N * HH * 2);       // layer GEMM bf16 out
    u16*   xcH    = (u16*)  alloc((size_t)N * 512 * 2);      // [x|f1|f2|f3] bf16
    u16*   WgtH   = (u16*)  alloc((size_t)NLAYERS * D * HH * 2);
    u16*   W1tH   = (u16*)  alloc((size_t)(D + NLAYERS * HH) * HH * 2);
    u16*   W2tH   = (u16*)  alloc((size_t)HH * CC * 2);
    u16*   W2tL   = (u16*)  alloc((size_t)HH * CC * 2);

    const int B = 256;
    const int gE = (E + B - 1) / B;
    const int nsb = (N + 1023) / 1024;

    // zero degree counts (stream-ordered; graph-capture legal)
    hipMemsetAsync(cnt, 0, (size_t)N * 4, stream);

    // fused prep: x->bf16 (x4) + all weight tilings + edge counting
    const int prepTotal = N * (D / 4) + NLAYERS * D * HH
                        + (D + NLAYERS * HH) * HH + HH * CC + E;
    k_prep<<<(prepTotal + B - 1) / B, B, 0, stream>>>(x, xcH, Wg, WgtH, W1, W1tH,
                                                      W2, W2tH, W2tL, dstp, cnt, N, E);
    k_scan_a<<<nsb, 1024, 0, stream>>>(cnt, rowptr, bsum, N);
    k_scan_c<<<(N + B - 1) / B, B, 0, stream>>>(rowptr, bsum, cnt, dinv, cursor, N, E, nsb);
    k_scatter<<<gE, B, 0, stream>>>(srcp, dstp, dinv, cursor, ecol, E);

    const int gemmBlocks = (N + 127) / 128;   // 2-tile blocks
    const int mlpBlocks  = (N + 63) / 64;
    const int aggBlocks  = 2048;              // persistent: 8192 waves x 2 nodes

    for (int l = 0; l < NLAYERS; ++l) {
        // hWb = bf16(h @ Wg[l])  (bias added after aggregation)
        k_gemm_lf<<<gemmBlocks, B, 0, stream>>>(xcH, l * HH,
                                                WgtH + (size_t)l * D * HH, hWb, N);
        k_agg_ln<<<aggBlocks, B, 0, stream>>>(hWb, rowptr, ecol, dinv,
                                              bg + (size_t)l * HH,
                                              lng + (size_t)l * HH,
                                              lnb + (size_t)l * HH,
                                              xcH + (size_t)(l + 1) * HH, N);
    }

    // out = softmax(relu([x|f1|f2|f3] @ W1 + b1) @ W2 + b2), fused
    k_mlp_fused<<<mlpBlocks, B, 0, stream>>>(xcH, W1tH, b1,
                                             W2tH, W2tL, b2, out, N);
}